// Round 4
// baseline (855.990 us; speedup 1.0000x reference)
//
#include <hip/hip_runtime.h>
#include <hip/hip_fp16.h>

#define N_USERS  200000
#define N_ITEMS  100000
#define N_TOPICS 100
#define N_NODES  (N_USERS + N_ITEMS + N_TOPICS)
#define DIM      64
#define SB       256                              // scan blocks
#define RCH      ((N_NODES + SB - 1) / SB)        // 1173 rows per scan block

// ---------- CSR build: direct global-atomic 2-pass ----------
// Rows are uniform-random (avg deg 16.6, no hot rows); global atomics run
// memory-side in L2. Hist atomics discard the return value (fire-and-forget,
// no vmcnt wait). This replaces the 4-kernel bucket-sort (which moved the
// 40-60 MB edge stream ~4x and cost ~290 us) with 2 edge passes.

__global__ void hist_kernel(const int* __restrict__ rows,
                            int* __restrict__ cnt, int n_edges) {
    int stride = gridDim.x * blockDim.x;
    for (int e = blockIdx.x * blockDim.x + threadIdx.x; e < n_edges; e += stride)
        atomicAdd(&cnt[rows[e]], 1);
}

__global__ void scanR1_kernel(const int* __restrict__ cnt,
                              int* __restrict__ psum) {
    __shared__ int s[256];
    int tid = threadIdx.x;
    int c0 = blockIdx.x * RCH;
    int c1 = min(N_NODES, c0 + RCH);
    int sum = 0;
    for (int i = c0 + tid; i < c1; i += 256) sum += cnt[i];
    s[tid] = sum;
    __syncthreads();
    for (int off = 128; off > 0; off >>= 1) {
        if (tid < off) s[tid] += s[tid + off];
        __syncthreads();
    }
    if (tid == 0) psum[blockIdx.x] = s[0];
}

// Each block derives its global base by reducing psum[0..bid), then scans its
// chunk, writing exclusive prefix to BOTH row_ptr and row_next (atomic cursor).
__global__ void scanR2_kernel(const int* __restrict__ cnt,
                              const int* __restrict__ psum,
                              int* __restrict__ row_ptr,
                              int* __restrict__ row_next, int n_edges) {
    __shared__ int s[SB];
    __shared__ int tile[256];
    __shared__ int carry;
    int tid = threadIdx.x;
    s[tid] = (tid < blockIdx.x) ? psum[tid] : 0;
    __syncthreads();
    for (int off = 128; off > 0; off >>= 1) {
        if (tid < off) s[tid] += s[tid + off];
        __syncthreads();
    }
    if (tid == 0) carry = s[0];
    __syncthreads();
    int c0 = blockIdx.x * RCH;
    int c1 = min(N_NODES, c0 + RCH);
    for (int base = c0; base < c1; base += 256) {
        int i = base + tid;
        int v = (i < c1) ? cnt[i] : 0;
        tile[tid] = v;
        __syncthreads();
        for (int off = 1; off < 256; off <<= 1) {
            int t = (tid >= off) ? tile[tid - off] : 0;
            __syncthreads();
            tile[tid] += t;
            __syncthreads();
        }
        if (i < c1) {
            int ex = carry + tile[tid] - v;
            row_ptr[i]  = ex;
            row_next[i] = ex;
        }
        __syncthreads();
        if (tid == 255) carry += tile[255];
        __syncthreads();
    }
    if (blockIdx.x == gridDim.x - 1 && tid == 0) row_ptr[N_NODES] = n_edges;
}

// One pass: claim slot via global atomic cursor, write {col, val}.
__global__ void scatter_csr_kernel(const int* __restrict__ rows,
                                   const int* __restrict__ cols,
                                   const float* __restrict__ vals,
                                   int* __restrict__ row_next,
                                   int2* __restrict__ csr_cv, int n_edges) {
    int stride = gridDim.x * blockDim.x;
    for (int e = blockIdx.x * blockDim.x + threadIdx.x; e < n_edges; e += stride) {
        int r = rows[e];
        int pos = atomicAdd(&row_next[r], 1);
        int2 cv;
        cv.x = cols[e];
        cv.y = __float_as_int(vals[e]);
        csr_cv[pos] = cv;
    }
}

// ---------- h0 = fp16(concat(user, item, topic)) ----------
__global__ void concat_f16_kernel(const float* __restrict__ uemb,
                                  const float* __restrict__ iemb,
                                  const float* __restrict__ temb,
                                  ushort* __restrict__ h0) {
    int g = blockIdx.x * blockDim.x + threadIdx.x;     // group of 4 elems
    long base = (long)g * 4;
    if (base >= (long)N_NODES * DIM) return;
    const float* src;
    long off;
    if (base < (long)N_USERS * DIM)                 { src = uemb; off = base; }
    else if (base < (long)(N_USERS + N_ITEMS) * DIM){ src = iemb; off = base - (long)N_USERS * DIM; }
    else                                            { src = temb; off = base - (long)(N_USERS + N_ITEMS) * DIM; }
    float4 v = *(const float4*)(src + off);
    __half2 a = __floats2half2_rn(v.x, v.y);
    __half2 b = __floats2half2_rn(v.z, v.w);
    uint2 o;
    o.x = *(unsigned*)&a;
    o.y = *(unsigned*)&b;
    ((uint2*)h0)[g] = o;
}

// ---------- SpMV helpers ----------
// fmaf(half2float(h), w, acc) lowers to v_fma_mix_f32 (fp16 src, fp32 MAC).
__device__ __forceinline__ float4 fma_mix4(const ushort* __restrict__ h,
                                           int row, int l16, float w,
                                           float4 acc) {
    uint2 r = ((const uint2*)(h + (size_t)row * DIM))[l16];
    __half2 h01 = *(__half2*)&r.x;
    __half2 h23 = *(__half2*)&r.y;
    acc.x = __builtin_fmaf(__half2float(__low2half(h01)),  w, acc.x);
    acc.y = __builtin_fmaf(__half2float(__high2half(h01)), w, acc.y);
    acc.z = __builtin_fmaf(__half2float(__low2half(h23)),  w, acc.z);
    acc.w = __builtin_fmaf(__half2float(__high2half(h23)), w, acc.w);
    return acc;
}

// Full-table SpMV: 4 rows/wave (1 per 16-lane group), 8 edges in flight.
// (8-unroll is the proven optimum: 16 raised VGPR 32->40, dropped occ
// 75->59% and added padding waste -> +23% time. Do not deepen.)
__global__ void spmv_csr_kernel(const int* __restrict__ row_ptr,
                                const int2* __restrict__ csr_cv,
                                const ushort* __restrict__ h_src,
                                ushort* __restrict__ h_dst) {
    int wave = (int)(((long)blockIdx.x * blockDim.x + threadIdx.x) >> 6);
    int lane = threadIdx.x & 63;
    int g    = lane >> 4;
    int l16  = lane & 15;
    int r    = wave * 4 + g;
    int rc   = min(r, N_NODES - 1);
    int p0   = row_ptr[rc];
    int p1   = row_ptr[rc + 1];
    int len  = (r < N_NODES) ? (p1 - p0) : 0;
    int m = max(len, __shfl_xor(len, 16, 64));
    m = max(m, __shfl_xor(m, 32, 64));
    float4 acc = make_float4(0.f, 0.f, 0.f, 0.f);
    for (int off = 0; off < m; off += 8) {
        int2 cv[8];
        #pragma unroll
        for (int j = 0; j < 8; ++j) {
            bool k = (off + j) < len;
            cv[j] = csr_cv[k ? (p0 + off + j) : p0];
            if (!k) cv[j].y = 0;
        }
        #pragma unroll
        for (int j = 0; j < 8; ++j)
            acc = fma_mix4(h_src, cv[j].x, l16, __int_as_float(cv[j].y), acc);
    }
    if (r < N_NODES) {
        __half2 a = __floats2half2_rn(acc.x, acc.y);
        __half2 b = __floats2half2_rn(acc.z, acc.w);
        uint2 o;
        o.x = *(unsigned*)&a;
        o.y = *(unsigned*)&b;
        ((uint2*)(h_dst + (size_t)r * DIM))[l16] = o;
    }
}

// Layer-3 SpMV over BATCH ROWS ONLY (~11% of the edges): slot s in [0,2B);
// node = users[s] or N_USERS+items[s-B]. Accumulates A·h2[node] in fp32 and
// adds straight into u_acc/it_acc (slot owned by exactly one group: safe RMW).
__global__ void spmv_batch_kernel(const int* __restrict__ row_ptr,
                                  const int2* __restrict__ csr_cv,
                                  const ushort* __restrict__ h_src,
                                  const int* __restrict__ users,
                                  const int* __restrict__ items,
                                  float* __restrict__ u_acc,
                                  float* __restrict__ it_acc, int B) {
    int wave = (int)(((long)blockIdx.x * blockDim.x + threadIdx.x) >> 6);
    int lane = threadIdx.x & 63;
    int g    = lane >> 4;
    int l16  = lane & 15;
    int s    = wave * 4 + g;
    bool ok  = s < 2 * B;
    int node = 0;
    if (ok) node = (s < B) ? users[s] : (N_USERS + items[s - B]);
    int p0  = row_ptr[node];
    int p1  = row_ptr[node + 1];
    int len = ok ? (p1 - p0) : 0;
    int m = max(len, __shfl_xor(len, 16, 64));
    m = max(m, __shfl_xor(m, 32, 64));
    float4 acc = make_float4(0.f, 0.f, 0.f, 0.f);
    for (int off = 0; off < m; off += 8) {
        int2 cv[8];
        #pragma unroll
        for (int j = 0; j < 8; ++j) {
            bool k = (off + j) < len;
            cv[j] = csr_cv[k ? (p0 + off + j) : p0];
            if (!k) cv[j].y = 0;
        }
        #pragma unroll
        for (int j = 0; j < 8; ++j)
            acc = fma_mix4(h_src, cv[j].x, l16, __int_as_float(cv[j].y), acc);
    }
    if (ok) {
        float* dst = (s < B) ? (u_acc + (size_t)s * DIM)
                             : (it_acc + (size_t)(s - B) * DIM);
        float4* p = (float4*)dst + l16;
        float4 old = *p;
        old.x += acc.x; old.y += acc.y; old.z += acc.z; old.w += acc.w;
        *p = old;
    }
}

// ---------- batch-row accumulation (fp32 acc) + readout ----------

__global__ void gather_add_kernel(const ushort* __restrict__ h,
                                  const int* __restrict__ users,
                                  const int* __restrict__ items,
                                  float* __restrict__ u_acc,
                                  float* __restrict__ it_acc,
                                  int B, int first) {
    int gid  = blockIdx.x * blockDim.x + threadIdx.x;
    int b    = gid >> 4;
    int lane = gid & 15;
    if (b >= B) return;
    int u  = users[b];
    int it = N_USERS + items[b];
    uint2 ur = ((const uint2*)(h + (size_t)u  * DIM))[lane];
    uint2 ir = ((const uint2*)(h + (size_t)it * DIM))[lane];
    float2 u01 = __half22float2(*(__half2*)&ur.x);
    float2 u23 = __half22float2(*(__half2*)&ur.y);
    float2 i01 = __half22float2(*(__half2*)&ir.x);
    float2 i23 = __half22float2(*(__half2*)&ir.y);
    float4* up = (float4*)(u_acc  + (size_t)b * DIM) + lane;
    float4* ip = (float4*)(it_acc + (size_t)b * DIM) + lane;
    if (first) {
        *up = make_float4(u01.x, u01.y, u23.x, u23.y);
        *ip = make_float4(i01.x, i01.y, i23.x, i23.y);
    } else {
        float4 a = *up;
        a.x += u01.x; a.y += u01.y; a.z += u23.x; a.w += u23.y;
        *up = a;
        float4 c = *ip;
        c.x += i01.x; c.y += i01.y; c.z += i23.x; c.w += i23.y;
        *ip = c;
    }
}

__global__ void dot_kernel(const float* __restrict__ u_acc,
                           const float* __restrict__ it_acc,
                           float* __restrict__ out, int B) {
    int gid  = blockIdx.x * blockDim.x + threadIdx.x;
    int b    = gid >> 6;
    int lane = gid & 63;
    if (b >= B) return;
    float p = u_acc[(size_t)b * DIM + lane] * it_acc[(size_t)b * DIM + lane];
    #pragma unroll
    for (int off = 32; off > 0; off >>= 1)
        p += __shfl_down(p, off, 64);
    if (lane == 0) out[b] = p * (1.0f / 16.0f);
}

extern "C" void kernel_launch(void* const* d_in, const int* in_sizes, int n_in,
                              void* d_out, int out_size, void* d_ws, size_t ws_size,
                              hipStream_t stream) {
    const int*   users = (const int*)d_in[0];
    const int*   items = (const int*)d_in[1];
    const int*   erows = (const int*)d_in[2];
    const int*   ecols = (const int*)d_in[3];
    const float* evals = (const float*)d_in[4];
    const float* uemb  = (const float*)d_in[5];
    const float* iemb  = (const float*)d_in[6];
    const float* temb  = (const float*)d_in[7];
    float* out = (float*)d_out;

    const int n_edges = in_sizes[2];
    const int B       = in_sizes[0];

    const size_t h2bytes = (((size_t)N_NODES * DIM * 2 + 255) / 256) * 256;  // 38.4 MB
    const size_t abytes  = (size_t)B * DIM * sizeof(float);                  // 4.2 MB
    const size_t rpbytes = (((size_t)(N_NODES + 1) * 4 + 255) / 256) * 256;
    const size_t cvbytes = (size_t)n_edges * 8;                              // 40 MB
    const size_t cbytes  = (((size_t)N_NODES * 4 + 255) / 256) * 256;        // 1.2 MB

    char* ws = (char*)d_ws;
    size_t off = 0;
    ushort* hA       = (ushort*)(ws + off); off += h2bytes;
    ushort* hB       = (ushort*)(ws + off); off += h2bytes;
    float*  u_acc    = (float*) (ws + off); off += abytes;
    float*  it_acc   = (float*) (ws + off); off += abytes;
    int*    row_ptr  = (int*)   (ws + off); off += rpbytes;
    int2*   csr_cv   = (int2*)  (ws + off); off += cvbytes;
    int*    row_cnt  = (int*)   (ws + off); off += cbytes;
    int*    row_next = (int*)   (ws + off); off += cbytes;
    int*    psum     = (int*)   (ws + off); off += 4096;

    dim3 blk(256);

    // ---- CSR build: direct global-atomic 2-pass ----
    hipMemsetAsync(row_cnt, 0, (size_t)N_NODES * 4, stream);
    hist_kernel<<<2048, blk, 0, stream>>>(erows, row_cnt, n_edges);
    scanR1_kernel<<<SB, blk, 0, stream>>>(row_cnt, psum);
    scanR2_kernel<<<SB, blk, 0, stream>>>(row_cnt, psum, row_ptr, row_next, n_edges);
    scatter_csr_kernel<<<2048, blk, 0, stream>>>(erows, ecols, evals,
                                                 row_next, csr_cv, n_edges);

    // ---- h0 ----
    const long n4 = (long)N_NODES * DIM / 4;
    concat_f16_kernel<<<(int)((n4 + 255) / 256), blk, 0, stream>>>(uemb, iemb, temb, hA);

    const int gblocks = (B * 16 + 255) / 256;
    gather_add_kernel<<<gblocks, blk, 0, stream>>>(hA, users, items, u_acc, it_acc, B, 1);

    // ---- layers 1,2: full-table SpMV; layer 3: batch rows only ----
    const int nwaves  = (N_NODES + 3) / 4;
    const int sblocks = (int)(((long)nwaves * 64 + 255) / 256);
    ushort* src = hA;
    ushort* dst = hB;
    for (int l = 0; l < 2; ++l) {
        spmv_csr_kernel<<<sblocks, blk, 0, stream>>>(row_ptr, csr_cv, src, dst);
        gather_add_kernel<<<gblocks, blk, 0, stream>>>(dst, users, items, u_acc, it_acc, B, 0);
        ushort* t = src; src = dst; dst = t;
    }
    // src == h2
    const int bwaves  = (2 * B + 3) / 4;
    const int bblocks = (int)(((long)bwaves * 64 + 255) / 256);
    spmv_batch_kernel<<<bblocks, blk, 0, stream>>>(row_ptr, csr_cv, src,
                                                   users, items, u_acc, it_acc, B);

    dot_kernel<<<(B * 64 + 255) / 256, blk, 0, stream>>>(u_acc, it_acc, out, B);
}

// Round 5
// 561.262 us; speedup vs baseline: 1.5251x; 1.5251x over previous
//
#include <hip/hip_runtime.h>
#include <hip/hip_fp16.h>

#define N_USERS  200000
#define N_ITEMS  100000
#define N_TOPICS 100
#define N_NODES  (N_USERS + N_ITEMS + N_TOPICS)
#define DIM      64
#define BSHIFT   9                                // 512 rows per bucket
#define BROWS    (1 << BSHIFT)
#define NBUCKETS ((N_NODES + BROWS - 1) >> BSHIFT)   // 587
#define COLMASK  0x7FFFF                          // 19 bits (N_NODES < 2^19)
#define NB       512                              // binning blocks
#define NBSHIFT  9
#define M_TOT    (NBUCKETS * NB)                  // 300,544 partials
#define SB       256                              // scan blocks
#define CH       ((M_TOT + SB - 1) / SB)
// Padded-CSR: each row padded to a multiple of 8 edges (zero-val entries);
// each bucket owns a fixed region. Bucket padded total ~10290 +- 106 (19
// sigma below 12288) -> no overflow for this dataset family.
#define BUCKET_CAP 12288

// ---------- CSR build (zero global atomics) ----------

// 512 threads/block (grid fixed at NB): 2x TLP vs 256, ~1 thread/LDS counter.
__global__ void bucket_hist_kernel(const int* __restrict__ rows,
                                   int* __restrict__ partial, int n_edges) {
    __shared__ int h[NBUCKETS];
    for (int i = threadIdx.x; i < NBUCKETS; i += blockDim.x) h[i] = 0;
    __syncthreads();
    int stride = gridDim.x * blockDim.x;
    for (int e = blockIdx.x * blockDim.x + threadIdx.x; e < n_edges; e += stride)
        atomicAdd(&h[((unsigned)rows[e]) >> BSHIFT], 1);
    __syncthreads();
    for (int i = threadIdx.x; i < NBUCKETS; i += blockDim.x)
        partial[blockIdx.x * NBUCKETS + i] = h[i];
}

// Logical L = bucket*NB + block; physical = block*NBUCKETS + bucket.
__device__ __forceinline__ int phys_idx(int L) {
    return (L & (NB - 1)) * NBUCKETS + (L >> NBSHIFT);
}

__global__ void scanB1_kernel(const int* __restrict__ partial,
                              int* __restrict__ psum) {
    __shared__ int s[256];
    int tid = threadIdx.x;
    int c0 = blockIdx.x * CH;
    int c1 = min(M_TOT, c0 + CH);
    int sum = 0;
    for (int L = c0 + tid; L < c1; L += 256) sum += partial[phys_idx(L)];
    s[tid] = sum;
    __syncthreads();
    for (int off = 128; off > 0; off >>= 1) {
        if (tid < off) s[tid] += s[tid + off];
        __syncthreads();
    }
    if (tid == 0) psum[blockIdx.x] = s[0];
}

// scanB2 folded in: each block reduces psum[0..bid) itself (256 ints, cheap).
__global__ void scanB3_kernel(const int* __restrict__ partial,
                              const int* __restrict__ psum,
                              int* __restrict__ offs) {
    __shared__ int s[SB];
    __shared__ int tile[256];
    __shared__ int carry;
    int tid = threadIdx.x;
    s[tid] = (tid < blockIdx.x) ? psum[tid] : 0;
    __syncthreads();
    for (int off = 128; off > 0; off >>= 1) {
        if (tid < off) s[tid] += s[tid + off];
        __syncthreads();
    }
    if (tid == 0) carry = s[0];
    __syncthreads();
    int c0 = blockIdx.x * CH;
    int c1 = min(M_TOT, c0 + CH);
    for (int base = c0; base < c1; base += 256) {
        int L = base + tid;
        int v = (L < c1) ? partial[phys_idx(L)] : 0;
        tile[tid] = v;
        __syncthreads();
        for (int off = 1; off < 256; off <<= 1) {
            int t = (tid >= off) ? tile[tid - off] : 0;
            __syncthreads();
            tile[tid] += t;
            __syncthreads();
        }
        if (L < c1) offs[L] = carry + tile[tid] - v;
        __syncthreads();
        if (tid == 255) carry += tile[255];
        __syncthreads();
    }
}

// Bin edges into 512-row buckets at exact positions; LDS-only atomics.
// 512 threads/block, grid fixed at NB (mapping must match bucket_hist).
__global__ void scatter1_kernel(const int* __restrict__ rows,
                                const int* __restrict__ cols,
                                const float* __restrict__ vals,
                                const int* __restrict__ offs,
                                int2* __restrict__ bkt_buf, int n_edges) {
    __shared__ int lpos[NBUCKETS];
    for (int i = threadIdx.x; i < NBUCKETS; i += blockDim.x)
        lpos[i] = offs[i * NB + blockIdx.x];
    __syncthreads();
    int stride = gridDim.x * blockDim.x;
    for (int e = blockIdx.x * blockDim.x + threadIdx.x; e < n_edges; e += stride) {
        int r = rows[e];
        int b = ((unsigned)r) >> BSHIFT;
        int pos = atomicAdd(&lpos[b], 1);
        int2 p;
        p.x = cols[e] | ((r & (BROWS - 1)) << 19);
        p.y = __float_as_int(vals[e]);
        bkt_buf[pos] = p;
    }
}

__device__ __forceinline__ int pad8(int x) { return (x + 7) & ~7; }

// One 512-thread block per 512-row bucket: LDS row hist, scan of PADDED
// counts, emit row_span = {beg, beg+pad8(cnt)}, place edges at
// bucket_base(b) + padded intra-bucket offsets, zero-fill the pad slots.
__global__ void scatter2_kernel(const int2* __restrict__ bkt_buf,
                                const int* __restrict__ offs,
                                int2* __restrict__ row_span,
                                int2* __restrict__ csr_cv, int n_edges) {
    __shared__ int lcnt[BROWS];
    __shared__ int lptr[BROWS];
    __shared__ int lfill[BROWS];
    __shared__ int s[256];
    int b = blockIdx.x;
    int t = threadIdx.x;
    int e0 = offs[b * NB];
    int e1 = (b == NBUCKETS - 1) ? n_edges : offs[(b + 1) * NB];
    lcnt[t] = 0;
    lfill[t] = 0;
    __syncthreads();
    for (int e = e0 + t; e < e1; e += blockDim.x)
        atomicAdd(&lcnt[((unsigned)bkt_buf[e].x) >> 19], 1);
    __syncthreads();
    if (t < 256) s[t] = pad8(lcnt[2 * t]) + pad8(lcnt[2 * t + 1]);
    __syncthreads();
    for (int off = 1; off < 256; off <<= 1) {
        int v = 0;
        if (t < 256 && t >= off) v = s[t - off];
        __syncthreads();
        if (t < 256) s[t] += v;          // inclusive over pairs
        __syncthreads();
    }
    if (t < 256) {
        int base = b * BUCKET_CAP + (t ? s[t - 1] : 0);
        int rbase = b << BSHIFT;
        int pe = pad8(lcnt[2 * t]);
        int po = pad8(lcnt[2 * t + 1]);
        int p_even = base;
        int p_odd  = base + pe;
        lptr[2 * t]     = p_even;
        lptr[2 * t + 1] = p_odd;
        if (rbase + 2 * t < N_NODES) {
            int2 sp; sp.x = p_even; sp.y = p_even + pe;
            row_span[rbase + 2 * t] = sp;
        }
        if (rbase + 2 * t + 1 < N_NODES) {
            int2 sp; sp.x = p_odd; sp.y = p_odd + po;
            row_span[rbase + 2 * t + 1] = sp;
        }
    }
    __syncthreads();
    for (int e = e0 + t; e < e1; e += blockDim.x) {
        int2 p = bkt_buf[e];
        int delta = ((unsigned)p.x) >> 19;
        int pos = lptr[delta] + atomicAdd(&lfill[delta], 1);
        int2 cv;
        cv.x = p.x & COLMASK;
        cv.y = p.y;
        csr_cv[pos] = cv;
    }
    __syncthreads();
    // zero-fill pad slots (col 0, val 0): one row per thread, <=7 each
    {
        int c  = lcnt[t];
        int cp = pad8(c);
        int p  = lptr[t];
        int2 z; z.x = 0; z.y = 0;
        for (int i = c; i < cp; ++i) csr_cv[p + i] = z;
    }
}

// ---------- h0 = fp16(concat(user, item, topic)) ----------
__global__ void concat_f16_kernel(const float* __restrict__ uemb,
                                  const float* __restrict__ iemb,
                                  const float* __restrict__ temb,
                                  ushort* __restrict__ h0) {
    int g = blockIdx.x * blockDim.x + threadIdx.x;     // group of 4 elems
    long base = (long)g * 4;
    if (base >= (long)N_NODES * DIM) return;
    const float* src;
    long off;
    if (base < (long)N_USERS * DIM)                 { src = uemb; off = base; }
    else if (base < (long)(N_USERS + N_ITEMS) * DIM){ src = iemb; off = base - (long)N_USERS * DIM; }
    else                                            { src = temb; off = base - (long)(N_USERS + N_ITEMS) * DIM; }
    float4 v = *(const float4*)(src + off);
    __half2 a = __floats2half2_rn(v.x, v.y);
    __half2 b = __floats2half2_rn(v.z, v.w);
    uint2 o;
    o.x = *(unsigned*)&a;
    o.y = *(unsigned*)&b;
    ((uint2*)h0)[g] = o;
}

// ---------- SpMV helpers ----------
// fmaf(half2float(h), w, acc) lowers to v_fma_mix_f32 (fp16 src, fp32 MAC).
__device__ __forceinline__ float4 fma_mix4(const ushort* __restrict__ h,
                                           int row, int l16, float w,
                                           float4 acc) {
    uint2 r = ((const uint2*)(h + (size_t)row * DIM))[l16];
    __half2 h01 = *(__half2*)&r.x;
    __half2 h23 = *(__half2*)&r.y;
    acc.x = __builtin_fmaf(__half2float(__low2half(h01)),  w, acc.x);
    acc.y = __builtin_fmaf(__half2float(__high2half(h01)), w, acc.y);
    acc.z = __builtin_fmaf(__half2float(__low2half(h23)),  w, acc.z);
    acc.w = __builtin_fmaf(__half2float(__high2half(h23)), w, acc.w);
    return acc;
}

// Process one 8-edge batch: 4 unconditional int4 loads (rows are padded to
// a multiple of 8 with zero-val entries -> no clamps, no ternaries).
__device__ __forceinline__ float4 batch8(const int2* __restrict__ csr_cv,
                                         const ushort* __restrict__ h_src,
                                         int p, int l16, float4 acc) {
    const int4* q = (const int4*)(csr_cv + p);
    int4 a = q[0], b = q[1], c = q[2], d = q[3];
    acc = fma_mix4(h_src, a.x, l16, __int_as_float(a.y), acc);
    acc = fma_mix4(h_src, a.z, l16, __int_as_float(a.w), acc);
    acc = fma_mix4(h_src, b.x, l16, __int_as_float(b.y), acc);
    acc = fma_mix4(h_src, b.z, l16, __int_as_float(b.w), acc);
    acc = fma_mix4(h_src, c.x, l16, __int_as_float(c.y), acc);
    acc = fma_mix4(h_src, c.z, l16, __int_as_float(c.w), acc);
    acc = fma_mix4(h_src, d.x, l16, __int_as_float(d.y), acc);
    acc = fma_mix4(h_src, d.z, l16, __int_as_float(d.w), acc);
    return acc;
}

// Full-table SpMV: 4 rows/wave (1 per 16-lane group), 8 edges in flight.
// (8-unroll is the proven optimum: 16 raised VGPR 32->40, dropped occ
// 75->59% and added padding waste -> +23% time. Do not deepen.)
__global__ void spmv_csr_kernel(const int2* __restrict__ row_span,
                                const int2* __restrict__ csr_cv,
                                const ushort* __restrict__ h_src,
                                ushort* __restrict__ h_dst) {
    int wave = (int)(((long)blockIdx.x * blockDim.x + threadIdx.x) >> 6);
    int lane = threadIdx.x & 63;
    int g    = lane >> 4;
    int l16  = lane & 15;
    int r    = wave * 4 + g;
    int rc   = min(r, N_NODES - 1);
    int2 sp  = row_span[rc];
    int p0   = sp.x;
    int len  = (r < N_NODES) ? (sp.y - sp.x) : 0;   // multiple of 8
    int m = max(len, __shfl_xor(len, 16, 64));
    m = max(m, __shfl_xor(m, 32, 64));
    float4 acc = make_float4(0.f, 0.f, 0.f, 0.f);
    for (int off = 0; off < m; off += 8) {
        if (off < len)
            acc = batch8(csr_cv, h_src, p0 + off, l16, acc);
    }
    if (r < N_NODES) {
        __half2 a = __floats2half2_rn(acc.x, acc.y);
        __half2 b = __floats2half2_rn(acc.z, acc.w);
        uint2 o;
        o.x = *(unsigned*)&a;
        o.y = *(unsigned*)&b;
        ((uint2*)(h_dst + (size_t)r * DIM))[l16] = o;
    }
}

// Layer-3 SpMV over BATCH ROWS ONLY (~11% of the edges): slot s in [0,2B);
// node = users[s] or N_USERS+items[s-B]. Accumulates A·h2[node] in fp32 and
// adds straight into u_acc/it_acc (slot owned by exactly one group: safe RMW).
__global__ void spmv_batch_kernel(const int2* __restrict__ row_span,
                                  const int2* __restrict__ csr_cv,
                                  const ushort* __restrict__ h_src,
                                  const int* __restrict__ users,
                                  const int* __restrict__ items,
                                  float* __restrict__ u_acc,
                                  float* __restrict__ it_acc, int B) {
    int wave = (int)(((long)blockIdx.x * blockDim.x + threadIdx.x) >> 6);
    int lane = threadIdx.x & 63;
    int g    = lane >> 4;
    int l16  = lane & 15;
    int s    = wave * 4 + g;
    bool ok  = s < 2 * B;
    int node = 0;
    if (ok) node = (s < B) ? users[s] : (N_USERS + items[s - B]);
    int2 sp  = row_span[node];
    int p0   = sp.x;
    int len  = ok ? (sp.y - sp.x) : 0;
    int m = max(len, __shfl_xor(len, 16, 64));
    m = max(m, __shfl_xor(m, 32, 64));
    float4 acc = make_float4(0.f, 0.f, 0.f, 0.f);
    for (int off = 0; off < m; off += 8) {
        if (off < len)
            acc = batch8(csr_cv, h_src, p0 + off, l16, acc);
    }
    if (ok) {
        float* dst = (s < B) ? (u_acc + (size_t)s * DIM)
                             : (it_acc + (size_t)(s - B) * DIM);
        float4* p = (float4*)dst + l16;
        float4 old = *p;
        old.x += acc.x; old.y += acc.y; old.z += acc.z; old.w += acc.w;
        *p = old;
    }
}

// ---------- batch-row accumulation (fp32 acc) + readout ----------

__global__ void gather_add_kernel(const ushort* __restrict__ h,
                                  const int* __restrict__ users,
                                  const int* __restrict__ items,
                                  float* __restrict__ u_acc,
                                  float* __restrict__ it_acc,
                                  int B, int first) {
    int gid  = blockIdx.x * blockDim.x + threadIdx.x;
    int b    = gid >> 4;
    int lane = gid & 15;
    if (b >= B) return;
    int u  = users[b];
    int it = N_USERS + items[b];
    uint2 ur = ((const uint2*)(h + (size_t)u  * DIM))[lane];
    uint2 ir = ((const uint2*)(h + (size_t)it * DIM))[lane];
    float2 u01 = __half22float2(*(__half2*)&ur.x);
    float2 u23 = __half22float2(*(__half2*)&ur.y);
    float2 i01 = __half22float2(*(__half2*)&ir.x);
    float2 i23 = __half22float2(*(__half2*)&ir.y);
    float4* up = (float4*)(u_acc  + (size_t)b * DIM) + lane;
    float4* ip = (float4*)(it_acc + (size_t)b * DIM) + lane;
    if (first) {
        *up = make_float4(u01.x, u01.y, u23.x, u23.y);
        *ip = make_float4(i01.x, i01.y, i23.x, i23.y);
    } else {
        float4 a = *up;
        a.x += u01.x; a.y += u01.y; a.z += u23.x; a.w += u23.y;
        *up = a;
        float4 c = *ip;
        c.x += i01.x; c.y += i01.y; c.z += i23.x; c.w += i23.y;
        *ip = c;
    }
}

__global__ void dot_kernel(const float* __restrict__ u_acc,
                           const float* __restrict__ it_acc,
                           float* __restrict__ out, int B) {
    int gid  = blockIdx.x * blockDim.x + threadIdx.x;
    int b    = gid >> 6;
    int lane = gid & 63;
    if (b >= B) return;
    float p = u_acc[(size_t)b * DIM + lane] * it_acc[(size_t)b * DIM + lane];
    #pragma unroll
    for (int off = 32; off > 0; off >>= 1)
        p += __shfl_down(p, off, 64);
    if (lane == 0) out[b] = p * (1.0f / 16.0f);
}

extern "C" void kernel_launch(void* const* d_in, const int* in_sizes, int n_in,
                              void* d_out, int out_size, void* d_ws, size_t ws_size,
                              hipStream_t stream) {
    const int*   users = (const int*)d_in[0];
    const int*   items = (const int*)d_in[1];
    const int*   erows = (const int*)d_in[2];
    const int*   ecols = (const int*)d_in[3];
    const float* evals = (const float*)d_in[4];
    const float* uemb  = (const float*)d_in[5];
    const float* iemb  = (const float*)d_in[6];
    const float* temb  = (const float*)d_in[7];
    float* out = (float*)d_out;

    const int n_edges = in_sizes[2];
    const int B       = in_sizes[0];

    const size_t h2bytes = (((size_t)N_NODES * DIM * 2 + 255) / 256) * 256;  // 38.4 MB
    const size_t abytes  = (size_t)B * DIM * sizeof(float);                  // 4.2 MB
    const size_t spbytes = (((size_t)N_NODES * 8 + 255) / 256) * 256;        // 2.4 MB
    const size_t csrbytes= (size_t)NBUCKETS * BUCKET_CAP * 8;                // 57.7 MB
    const size_t bkbytes = (size_t)n_edges * 8;                              // 40 MB
    const size_t mbytes  = (((size_t)M_TOT * 4 + 255) / 256) * 256;          // 1.2 MB

    char* ws = (char*)d_ws;
    size_t off = 0;
    ushort* hA       = (ushort*)(ws + off); off += h2bytes;
    ushort* hB       = (ushort*)(ws + off); off += h2bytes;
    float*  u_acc    = (float*) (ws + off); off += abytes;
    float*  it_acc   = (float*) (ws + off); off += abytes;
    int2*   row_span = (int2*)  (ws + off); off += spbytes;
    int2*   csr_cv   = (int2*)  (ws + off); off += csrbytes;
    int2*   bkt_buf  = (int2*)  (ws + off); off += bkbytes;
    int*    partial  = (int*)   (ws + off); off += mbytes;
    int*    offs     = (int*)   (ws + off); off += mbytes;
    int*    psum     = (int*)   (ws + off); off += 4096;   // ~186 MB total

    dim3 blk(256);
    dim3 blk512(512);

    // ---- CSR build: zero global atomics ----
    bucket_hist_kernel<<<NB, blk512, 0, stream>>>(erows, partial, n_edges);
    scanB1_kernel<<<SB, blk, 0, stream>>>(partial, psum);
    scanB3_kernel<<<SB, blk, 0, stream>>>(partial, psum, offs);
    scatter1_kernel<<<NB, blk512, 0, stream>>>(erows, ecols, evals, offs, bkt_buf, n_edges);
    scatter2_kernel<<<NBUCKETS, blk512, 0, stream>>>(bkt_buf, offs, row_span, csr_cv, n_edges);

    // ---- h0 ----
    const long n4 = (long)N_NODES * DIM / 4;
    concat_f16_kernel<<<(int)((n4 + 255) / 256), blk, 0, stream>>>(uemb, iemb, temb, hA);

    const int gblocks = (B * 16 + 255) / 256;
    gather_add_kernel<<<gblocks, blk, 0, stream>>>(hA, users, items, u_acc, it_acc, B, 1);

    // ---- layers 1,2: full-table SpMV; layer 3: batch rows only ----
    const int nwaves  = (N_NODES + 3) / 4;
    const int sblocks = (int)(((long)nwaves * 64 + 255) / 256);
    ushort* src = hA;
    ushort* dst = hB;
    for (int l = 0; l < 2; ++l) {
        spmv_csr_kernel<<<sblocks, blk, 0, stream>>>(row_span, csr_cv, src, dst);
        gather_add_kernel<<<gblocks, blk, 0, stream>>>(dst, users, items, u_acc, it_acc, B, 0);
        ushort* t = src; src = dst; dst = t;
    }
    // src == h2
    const int bwaves  = (2 * B + 3) / 4;
    const int bblocks = (int)(((long)bwaves * 64 + 255) / 256);
    spmv_batch_kernel<<<bblocks, blk, 0, stream>>>(row_span, csr_cv, src,
                                                   users, items, u_acc, it_acc, B);

    dot_kernel<<<(B * 64 + 255) / 256, blk, 0, stream>>>(u_acc, it_acc, out, B);
}

// Round 6
// 548.497 us; speedup vs baseline: 1.5606x; 1.0233x over previous
//
#include <hip/hip_runtime.h>
#include <hip/hip_fp16.h>

#define N_USERS  200000
#define N_ITEMS  100000
#define N_TOPICS 100
#define N_NODES  (N_USERS + N_ITEMS + N_TOPICS)
#define DIM      64
#define BSHIFT   10                               // 1024 rows per bucket
#define BROWS    (1 << BSHIFT)
#define NBUCKETS ((N_NODES + BROWS - 1) >> BSHIFT)   // 294
#define COLMASK  0x7FFFF                          // 19 bits (N_NODES < 2^19)
#define NB       512                              // binning blocks
#define NBSHIFT  9
#define M_TOT    (NBUCKETS * NB)                  // 150,528 partials
#define SB       256                              // scan blocks
#define CH       ((M_TOT + SB - 1) / SB)
// Padded-CSR: each row padded to a multiple of 8 edges (zero-val entries);
// each bucket owns a fixed region. Bucket padded total ~20650 +- ~140 (28
// sigma below 24576) -> no overflow for this dataset family.
#define BUCKET_CAP 24576

// BSHIFT=10 rationale: scatter1's write-amplification (136 MB HBM for 40 MB
// payload at BSHIFT=9) comes from 64 blocks/XCD x 587 cursor lines = 4.8 MB
// active set > 4 MB per-XCD L2. At 294 buckets: 2.4 MB -> lines fill before
// eviction.

// ---------- CSR build (zero global atomics) ----------

__global__ void bucket_hist_kernel(const int* __restrict__ rows,
                                   int* __restrict__ partial, int n_edges) {
    __shared__ int h[NBUCKETS];
    for (int i = threadIdx.x; i < NBUCKETS; i += blockDim.x) h[i] = 0;
    __syncthreads();
    int stride = gridDim.x * blockDim.x;
    for (int e = blockIdx.x * blockDim.x + threadIdx.x; e < n_edges; e += stride)
        atomicAdd(&h[((unsigned)rows[e]) >> BSHIFT], 1);
    __syncthreads();
    for (int i = threadIdx.x; i < NBUCKETS; i += blockDim.x)
        partial[blockIdx.x * NBUCKETS + i] = h[i];
}

// Logical L = bucket*NB + block; physical = block*NBUCKETS + bucket.
__device__ __forceinline__ int phys_idx(int L) {
    return (L & (NB - 1)) * NBUCKETS + (L >> NBSHIFT);
}

__global__ void scanB1_kernel(const int* __restrict__ partial,
                              int* __restrict__ psum) {
    __shared__ int s[256];
    int tid = threadIdx.x;
    int c0 = blockIdx.x * CH;
    int c1 = min(M_TOT, c0 + CH);
    int sum = 0;
    for (int L = c0 + tid; L < c1; L += 256) sum += partial[phys_idx(L)];
    s[tid] = sum;
    __syncthreads();
    for (int off = 128; off > 0; off >>= 1) {
        if (tid < off) s[tid] += s[tid + off];
        __syncthreads();
    }
    if (tid == 0) psum[blockIdx.x] = s[0];
}

// scanB2 folded in: each block reduces psum[0..bid) itself (256 ints, cheap).
__global__ void scanB3_kernel(const int* __restrict__ partial,
                              const int* __restrict__ psum,
                              int* __restrict__ offs) {
    __shared__ int s[SB];
    __shared__ int tile[256];
    __shared__ int carry;
    int tid = threadIdx.x;
    s[tid] = (tid < blockIdx.x) ? psum[tid] : 0;
    __syncthreads();
    for (int off = 128; off > 0; off >>= 1) {
        if (tid < off) s[tid] += s[tid + off];
        __syncthreads();
    }
    if (tid == 0) carry = s[0];
    __syncthreads();
    int c0 = blockIdx.x * CH;
    int c1 = min(M_TOT, c0 + CH);
    for (int base = c0; base < c1; base += 256) {
        int L = base + tid;
        int v = (L < c1) ? partial[phys_idx(L)] : 0;
        tile[tid] = v;
        __syncthreads();
        for (int off = 1; off < 256; off <<= 1) {
            int t = (tid >= off) ? tile[tid - off] : 0;
            __syncthreads();
            tile[tid] += t;
            __syncthreads();
        }
        if (L < c1) offs[L] = carry + tile[tid] - v;
        __syncthreads();
        if (tid == 255) carry += tile[255];
        __syncthreads();
    }
}

// Bin edges into 1024-row buckets at exact positions; LDS-only atomics.
// 512 threads/block, grid fixed at NB (mapping must match bucket_hist).
__global__ void scatter1_kernel(const int* __restrict__ rows,
                                const int* __restrict__ cols,
                                const float* __restrict__ vals,
                                const int* __restrict__ offs,
                                int2* __restrict__ bkt_buf, int n_edges) {
    __shared__ int lpos[NBUCKETS];
    for (int i = threadIdx.x; i < NBUCKETS; i += blockDim.x)
        lpos[i] = offs[i * NB + blockIdx.x];
    __syncthreads();
    int stride = gridDim.x * blockDim.x;
    for (int e = blockIdx.x * blockDim.x + threadIdx.x; e < n_edges; e += stride) {
        int r = rows[e];
        int b = ((unsigned)r) >> BSHIFT;
        int pos = atomicAdd(&lpos[b], 1);
        int2 p;
        p.x = cols[e] | ((r & (BROWS - 1)) << 19);   // 19+10 bits < 32
        p.y = __float_as_int(vals[e]);
        bkt_buf[pos] = p;
    }
}

__device__ __forceinline__ int pad8(int x) { return (x + 7) & ~7; }

// One 512-thread block per 1024-row bucket: LDS row hist, 512-wide scan of
// PADDED pair-counts, emit row_span = {beg, beg+pad8(cnt)}, place edges at
// bucket_base(b) + padded intra-bucket offsets, zero-fill the pad slots.
__global__ void scatter2_kernel(const int2* __restrict__ bkt_buf,
                                const int* __restrict__ offs,
                                int2* __restrict__ row_span,
                                int2* __restrict__ csr_cv, int n_edges) {
    __shared__ int lcnt[BROWS];
    __shared__ int lptr[BROWS];
    __shared__ int lfill[BROWS];
    __shared__ int s[512];
    int b = blockIdx.x;
    int t = threadIdx.x;
    int e0 = offs[b * NB];
    int e1 = (b == NBUCKETS - 1) ? n_edges : offs[(b + 1) * NB];
    for (int i = t; i < BROWS; i += 512) { lcnt[i] = 0; lfill[i] = 0; }
    __syncthreads();
    for (int e = e0 + t; e < e1; e += blockDim.x)
        atomicAdd(&lcnt[((unsigned)bkt_buf[e].x) >> 19], 1);
    __syncthreads();
    s[t] = pad8(lcnt[2 * t]) + pad8(lcnt[2 * t + 1]);
    __syncthreads();
    for (int off = 1; off < 512; off <<= 1) {
        int v = (t >= off) ? s[t - off] : 0;
        __syncthreads();
        s[t] += v;                       // inclusive over pairs
        __syncthreads();
    }
    {
        int base = b * BUCKET_CAP + (t ? s[t - 1] : 0);
        int rbase = b << BSHIFT;
        int pe = pad8(lcnt[2 * t]);
        int po = pad8(lcnt[2 * t + 1]);
        int p_even = base;
        int p_odd  = base + pe;
        lptr[2 * t]     = p_even;
        lptr[2 * t + 1] = p_odd;
        if (rbase + 2 * t < N_NODES) {
            int2 sp; sp.x = p_even; sp.y = p_even + pe;
            row_span[rbase + 2 * t] = sp;
        }
        if (rbase + 2 * t + 1 < N_NODES) {
            int2 sp; sp.x = p_odd; sp.y = p_odd + po;
            row_span[rbase + 2 * t + 1] = sp;
        }
    }
    __syncthreads();
    for (int e = e0 + t; e < e1; e += blockDim.x) {
        int2 p = bkt_buf[e];
        int delta = ((unsigned)p.x) >> 19;
        int pos = lptr[delta] + atomicAdd(&lfill[delta], 1);
        int2 cv;
        cv.x = p.x & COLMASK;
        cv.y = p.y;
        csr_cv[pos] = cv;
    }
    __syncthreads();
    // zero-fill pad slots (col 0, val 0): two rows per thread, <=7 each
    for (int i = t; i < BROWS; i += 512) {
        int c  = lcnt[i];
        int cp = pad8(c);
        int p  = lptr[i];
        int2 z; z.x = 0; z.y = 0;
        for (int k = c; k < cp; ++k) csr_cv[p + k] = z;
    }
}

// ---------- h0 = fp16(concat(user, item, topic)) ----------
__global__ void concat_f16_kernel(const float* __restrict__ uemb,
                                  const float* __restrict__ iemb,
                                  const float* __restrict__ temb,
                                  ushort* __restrict__ h0) {
    int g = blockIdx.x * blockDim.x + threadIdx.x;     // group of 4 elems
    long base = (long)g * 4;
    if (base >= (long)N_NODES * DIM) return;
    const float* src;
    long off;
    if (base < (long)N_USERS * DIM)                 { src = uemb; off = base; }
    else if (base < (long)(N_USERS + N_ITEMS) * DIM){ src = iemb; off = base - (long)N_USERS * DIM; }
    else                                            { src = temb; off = base - (long)(N_USERS + N_ITEMS) * DIM; }
    float4 v = *(const float4*)(src + off);
    __half2 a = __floats2half2_rn(v.x, v.y);
    __half2 b = __floats2half2_rn(v.z, v.w);
    uint2 o;
    o.x = *(unsigned*)&a;
    o.y = *(unsigned*)&b;
    ((uint2*)h0)[g] = o;
}

// ---------- SpMV helpers ----------
// fmaf(half2float(h), w, acc) lowers to v_fma_mix_f32 (fp16 src, fp32 MAC).
__device__ __forceinline__ float4 fma_mix4(const ushort* __restrict__ h,
                                           int row, int l16, float w,
                                           float4 acc) {
    uint2 r = ((const uint2*)(h + (size_t)row * DIM))[l16];
    __half2 h01 = *(__half2*)&r.x;
    __half2 h23 = *(__half2*)&r.y;
    acc.x = __builtin_fmaf(__half2float(__low2half(h01)),  w, acc.x);
    acc.y = __builtin_fmaf(__half2float(__high2half(h01)), w, acc.y);
    acc.z = __builtin_fmaf(__half2float(__low2half(h23)),  w, acc.z);
    acc.w = __builtin_fmaf(__half2float(__high2half(h23)), w, acc.w);
    return acc;
}

// Process one 8-edge batch: 4 unconditional int4 loads (rows are padded to
// a multiple of 8 with zero-val entries -> no clamps, no ternaries).
__device__ __forceinline__ float4 batch8(const int2* __restrict__ csr_cv,
                                         const ushort* __restrict__ h_src,
                                         int p, int l16, float4 acc) {
    const int4* q = (const int4*)(csr_cv + p);
    int4 a = q[0], b = q[1], c = q[2], d = q[3];
    acc = fma_mix4(h_src, a.x, l16, __int_as_float(a.y), acc);
    acc = fma_mix4(h_src, a.z, l16, __int_as_float(a.w), acc);
    acc = fma_mix4(h_src, b.x, l16, __int_as_float(b.y), acc);
    acc = fma_mix4(h_src, b.z, l16, __int_as_float(b.w), acc);
    acc = fma_mix4(h_src, c.x, l16, __int_as_float(c.y), acc);
    acc = fma_mix4(h_src, c.z, l16, __int_as_float(c.w), acc);
    acc = fma_mix4(h_src, d.x, l16, __int_as_float(d.y), acc);
    acc = fma_mix4(h_src, d.z, l16, __int_as_float(d.w), acc);
    return acc;
}

// Full-table SpMV: 4 rows/wave (1 per 16-lane group), 8 edges in flight.
// (8-unroll is the proven optimum: 16 raised VGPR 32->40, dropped occ
// 75->59% and added padding waste -> +23% time. Do not deepen.)
__global__ void spmv_csr_kernel(const int2* __restrict__ row_span,
                                const int2* __restrict__ csr_cv,
                                const ushort* __restrict__ h_src,
                                ushort* __restrict__ h_dst) {
    int wave = (int)(((long)blockIdx.x * blockDim.x + threadIdx.x) >> 6);
    int lane = threadIdx.x & 63;
    int g    = lane >> 4;
    int l16  = lane & 15;
    int r    = wave * 4 + g;
    int rc   = min(r, N_NODES - 1);
    int2 sp  = row_span[rc];
    int p0   = sp.x;
    int len  = (r < N_NODES) ? (sp.y - sp.x) : 0;   // multiple of 8
    int m = max(len, __shfl_xor(len, 16, 64));
    m = max(m, __shfl_xor(m, 32, 64));
    float4 acc = make_float4(0.f, 0.f, 0.f, 0.f);
    for (int off = 0; off < m; off += 8) {
        if (off < len)
            acc = batch8(csr_cv, h_src, p0 + off, l16, acc);
    }
    if (r < N_NODES) {
        __half2 a = __floats2half2_rn(acc.x, acc.y);
        __half2 b = __floats2half2_rn(acc.z, acc.w);
        uint2 o;
        o.x = *(unsigned*)&a;
        o.y = *(unsigned*)&b;
        ((uint2*)(h_dst + (size_t)r * DIM))[l16] = o;
    }
}

// Layer-3 SpMV over BATCH ROWS ONLY (~11% of the edges): slot s in [0,2B);
// node = users[s] or N_USERS+items[s-B]. Accumulates A·h2[node] in fp32 and
// adds straight into u_acc/it_acc (slot owned by exactly one group: safe RMW).
__global__ void spmv_batch_kernel(const int2* __restrict__ row_span,
                                  const int2* __restrict__ csr_cv,
                                  const ushort* __restrict__ h_src,
                                  const int* __restrict__ users,
                                  const int* __restrict__ items,
                                  float* __restrict__ u_acc,
                                  float* __restrict__ it_acc, int B) {
    int wave = (int)(((long)blockIdx.x * blockDim.x + threadIdx.x) >> 6);
    int lane = threadIdx.x & 63;
    int g    = lane >> 4;
    int l16  = lane & 15;
    int s    = wave * 4 + g;
    bool ok  = s < 2 * B;
    int node = 0;
    if (ok) node = (s < B) ? users[s] : (N_USERS + items[s - B]);
    int2 sp  = row_span[node];
    int p0   = sp.x;
    int len  = ok ? (sp.y - sp.x) : 0;
    int m = max(len, __shfl_xor(len, 16, 64));
    m = max(m, __shfl_xor(m, 32, 64));
    float4 acc = make_float4(0.f, 0.f, 0.f, 0.f);
    for (int off = 0; off < m; off += 8) {
        if (off < len)
            acc = batch8(csr_cv, h_src, p0 + off, l16, acc);
    }
    if (ok) {
        float* dst = (s < B) ? (u_acc + (size_t)s * DIM)
                             : (it_acc + (size_t)(s - B) * DIM);
        float4* p = (float4*)dst + l16;
        float4 old = *p;
        old.x += acc.x; old.y += acc.y; old.z += acc.z; old.w += acc.w;
        *p = old;
    }
}

// ---------- batch-row accumulation (fp32 acc) + readout ----------

__global__ void gather_add_kernel(const ushort* __restrict__ h,
                                  const int* __restrict__ users,
                                  const int* __restrict__ items,
                                  float* __restrict__ u_acc,
                                  float* __restrict__ it_acc,
                                  int B, int first) {
    int gid  = blockIdx.x * blockDim.x + threadIdx.x;
    int b    = gid >> 4;
    int lane = gid & 15;
    if (b >= B) return;
    int u  = users[b];
    int it = N_USERS + items[b];
    uint2 ur = ((const uint2*)(h + (size_t)u  * DIM))[lane];
    uint2 ir = ((const uint2*)(h + (size_t)it * DIM))[lane];
    float2 u01 = __half22float2(*(__half2*)&ur.x);
    float2 u23 = __half22float2(*(__half2*)&ur.y);
    float2 i01 = __half22float2(*(__half2*)&ir.x);
    float2 i23 = __half22float2(*(__half2*)&ir.y);
    float4* up = (float4*)(u_acc  + (size_t)b * DIM) + lane;
    float4* ip = (float4*)(it_acc + (size_t)b * DIM) + lane;
    if (first) {
        *up = make_float4(u01.x, u01.y, u23.x, u23.y);
        *ip = make_float4(i01.x, i01.y, i23.x, i23.y);
    } else {
        float4 a = *up;
        a.x += u01.x; a.y += u01.y; a.z += u23.x; a.w += u23.y;
        *up = a;
        float4 c = *ip;
        c.x += i01.x; c.y += i01.y; c.z += i23.x; c.w += i23.y;
        *ip = c;
    }
}

__global__ void dot_kernel(const float* __restrict__ u_acc,
                           const float* __restrict__ it_acc,
                           float* __restrict__ out, int B) {
    int gid  = blockIdx.x * blockDim.x + threadIdx.x;
    int b    = gid >> 6;
    int lane = gid & 63;
    if (b >= B) return;
    float p = u_acc[(size_t)b * DIM + lane] * it_acc[(size_t)b * DIM + lane];
    #pragma unroll
    for (int off = 32; off > 0; off >>= 1)
        p += __shfl_down(p, off, 64);
    if (lane == 0) out[b] = p * (1.0f / 16.0f);
}

extern "C" void kernel_launch(void* const* d_in, const int* in_sizes, int n_in,
                              void* d_out, int out_size, void* d_ws, size_t ws_size,
                              hipStream_t stream) {
    const int*   users = (const int*)d_in[0];
    const int*   items = (const int*)d_in[1];
    const int*   erows = (const int*)d_in[2];
    const int*   ecols = (const int*)d_in[3];
    const float* evals = (const float*)d_in[4];
    const float* uemb  = (const float*)d_in[5];
    const float* iemb  = (const float*)d_in[6];
    const float* temb  = (const float*)d_in[7];
    float* out = (float*)d_out;

    const int n_edges = in_sizes[2];
    const int B       = in_sizes[0];

    const size_t h2bytes = (((size_t)N_NODES * DIM * 2 + 255) / 256) * 256;  // 38.4 MB
    const size_t abytes  = (size_t)B * DIM * sizeof(float);                  // 4.2 MB
    const size_t spbytes = (((size_t)N_NODES * 8 + 255) / 256) * 256;        // 2.4 MB
    const size_t csrbytes= (size_t)NBUCKETS * BUCKET_CAP * 8;                // 57.8 MB
    const size_t bkbytes = (size_t)n_edges * 8;                              // 40 MB
    const size_t mbytes  = (((size_t)M_TOT * 4 + 255) / 256) * 256;          // 0.6 MB

    char* ws = (char*)d_ws;
    size_t off = 0;
    ushort* hA       = (ushort*)(ws + off); off += h2bytes;
    ushort* hB       = (ushort*)(ws + off); off += h2bytes;
    float*  u_acc    = (float*) (ws + off); off += abytes;
    float*  it_acc   = (float*) (ws + off); off += abytes;
    int2*   row_span = (int2*)  (ws + off); off += spbytes;
    int2*   csr_cv   = (int2*)  (ws + off); off += csrbytes;
    int2*   bkt_buf  = (int2*)  (ws + off); off += bkbytes;
    int*    partial  = (int*)   (ws + off); off += mbytes;
    int*    offs     = (int*)   (ws + off); off += mbytes;
    int*    psum     = (int*)   (ws + off); off += 4096;   // ~186 MB total

    dim3 blk(256);
    dim3 blk512(512);

    // ---- CSR build: zero global atomics ----
    bucket_hist_kernel<<<NB, blk512, 0, stream>>>(erows, partial, n_edges);
    scanB1_kernel<<<SB, blk, 0, stream>>>(partial, psum);
    scanB3_kernel<<<SB, blk, 0, stream>>>(partial, psum, offs);
    scatter1_kernel<<<NB, blk512, 0, stream>>>(erows, ecols, evals, offs, bkt_buf, n_edges);
    scatter2_kernel<<<NBUCKETS, blk512, 0, stream>>>(bkt_buf, offs, row_span, csr_cv, n_edges);

    // ---- h0 ----
    const long n4 = (long)N_NODES * DIM / 4;
    concat_f16_kernel<<<(int)((n4 + 255) / 256), blk, 0, stream>>>(uemb, iemb, temb, hA);

    const int gblocks = (B * 16 + 255) / 256;
    gather_add_kernel<<<gblocks, blk, 0, stream>>>(hA, users, items, u_acc, it_acc, B, 1);

    // ---- layers 1,2: full-table SpMV; layer 3: batch rows only ----
    const int nwaves  = (N_NODES + 3) / 4;
    const int sblocks = (int)(((long)nwaves * 64 + 255) / 256);
    ushort* src = hA;
    ushort* dst = hB;
    for (int l = 0; l < 2; ++l) {
        spmv_csr_kernel<<<sblocks, blk, 0, stream>>>(row_span, csr_cv, src, dst);
        gather_add_kernel<<<gblocks, blk, 0, stream>>>(dst, users, items, u_acc, it_acc, B, 0);
        ushort* t = src; src = dst; dst = t;
    }
    // src == h2
    const int bwaves  = (2 * B + 3) / 4;
    const int bblocks = (int)(((long)bwaves * 64 + 255) / 256);
    spmv_batch_kernel<<<bblocks, blk, 0, stream>>>(row_span, csr_cv, src,
                                                   users, items, u_acc, it_acc, B);

    dot_kernel<<<(B * 64 + 255) / 256, blk, 0, stream>>>(u_acc, it_acc, out, B);
}

// Round 7
// 524.351 us; speedup vs baseline: 1.6325x; 1.0461x over previous
//
#include <hip/hip_runtime.h>
#include <hip/hip_fp16.h>

#define N_USERS  200000
#define N_ITEMS  100000
#define N_TOPICS 100
#define N_NODES  (N_USERS + N_ITEMS + N_TOPICS)
#define DIM      64
#define BSHIFT   10                               // 1024 rows per bucket
#define BROWS    (1 << BSHIFT)
#define NBUCKETS ((N_NODES + BROWS - 1) >> BSHIFT)   // 294
#define COLMASK  0x7FFFF                          // 19 bits (N_NODES < 2^19)
#define NB       512                              // binning blocks
#define NBSHIFT  9
#define M_TOT    (NBUCKETS * NB)                  // 150,528 partials
#define SB       256                              // scan blocks
#define CH       ((M_TOT + SB - 1) / SB)
// Padded-CSR: each row padded to a multiple of 8 edges (zero-val entries);
// each bucket owns a fixed region. Bucket padded total ~20650 +- ~140 (28
// sigma below 24576) -> no overflow for this dataset family.
#define BUCKET_CAP 24576

// BSHIFT=10 rationale (confirmed r6): scatter1's write-amplification at
// BSHIFT=9 (136 MB HBM for 40 MB payload) came from 64 blocks/XCD x 587
// cursor lines = 4.8 MB active set > 4 MB per-XCD L2. At 294 buckets:
// 2.4 MB -> cursor lines fill before eviction.

// ---------- prep: bucket hist (blocks [0,NB)) + h0 concat (rest) ----------

__global__ void prep_kernel(const int* __restrict__ rows,
                            int* __restrict__ partial, int n_edges,
                            const float* __restrict__ uemb,
                            const float* __restrict__ iemb,
                            const float* __restrict__ temb,
                            ushort* __restrict__ h0) {
    __shared__ int h[NBUCKETS];
    if (blockIdx.x < NB) {
        for (int i = threadIdx.x; i < NBUCKETS; i += blockDim.x) h[i] = 0;
        __syncthreads();
        int stride = NB * blockDim.x;
        for (int e = blockIdx.x * blockDim.x + threadIdx.x; e < n_edges; e += stride)
            atomicAdd(&h[((unsigned)rows[e]) >> BSHIFT], 1);
        __syncthreads();
        for (int i = threadIdx.x; i < NBUCKETS; i += blockDim.x)
            partial[blockIdx.x * NBUCKETS + i] = h[i];
    } else {
        int g = (blockIdx.x - NB) * blockDim.x + threadIdx.x;  // group of 4
        long base = (long)g * 4;
        if (base >= (long)N_NODES * DIM) return;
        const float* src;
        long off;
        if (base < (long)N_USERS * DIM)                 { src = uemb; off = base; }
        else if (base < (long)(N_USERS + N_ITEMS) * DIM){ src = iemb; off = base - (long)N_USERS * DIM; }
        else                                            { src = temb; off = base - (long)(N_USERS + N_ITEMS) * DIM; }
        float4 v = *(const float4*)(src + off);
        __half2 a = __floats2half2_rn(v.x, v.y);
        __half2 b = __floats2half2_rn(v.z, v.w);
        uint2 o;
        o.x = *(unsigned*)&a;
        o.y = *(unsigned*)&b;
        ((uint2*)h0)[g] = o;
    }
}

// Logical L = bucket*NB + block; physical = block*NBUCKETS + bucket.
__device__ __forceinline__ int phys_idx(int L) {
    return (L & (NB - 1)) * NBUCKETS + (L >> NBSHIFT);
}

__global__ void scanB1_kernel(const int* __restrict__ partial,
                              int* __restrict__ psum) {
    __shared__ int s[256];
    int tid = threadIdx.x;
    int c0 = blockIdx.x * CH;
    int c1 = min(M_TOT, c0 + CH);
    int sum = 0;
    for (int L = c0 + tid; L < c1; L += 256) sum += partial[phys_idx(L)];
    s[tid] = sum;
    __syncthreads();
    for (int off = 128; off > 0; off >>= 1) {
        if (tid < off) s[tid] += s[tid + off];
        __syncthreads();
    }
    if (tid == 0) psum[blockIdx.x] = s[0];
}

// scanB2 folded in: each block reduces psum[0..bid) itself (256 ints, cheap).
__global__ void scanB3_kernel(const int* __restrict__ partial,
                              const int* __restrict__ psum,
                              int* __restrict__ offs) {
    __shared__ int s[SB];
    __shared__ int tile[256];
    __shared__ int carry;
    int tid = threadIdx.x;
    s[tid] = (tid < blockIdx.x) ? psum[tid] : 0;
    __syncthreads();
    for (int off = 128; off > 0; off >>= 1) {
        if (tid < off) s[tid] += s[tid + off];
        __syncthreads();
    }
    if (tid == 0) carry = s[0];
    __syncthreads();
    int c0 = blockIdx.x * CH;
    int c1 = min(M_TOT, c0 + CH);
    for (int base = c0; base < c1; base += 256) {
        int L = base + tid;
        int v = (L < c1) ? partial[phys_idx(L)] : 0;
        tile[tid] = v;
        __syncthreads();
        for (int off = 1; off < 256; off <<= 1) {
            int t = (tid >= off) ? tile[tid - off] : 0;
            __syncthreads();
            tile[tid] += t;
            __syncthreads();
        }
        if (L < c1) offs[L] = carry + tile[tid] - v;
        __syncthreads();
        if (tid == 255) carry += tile[255];
        __syncthreads();
    }
}

// Bin edges into 1024-row buckets at exact positions; LDS-only atomics.
// 512 threads/block, grid fixed at NB (mapping must match prep hist part).
__global__ void scatter1_kernel(const int* __restrict__ rows,
                                const int* __restrict__ cols,
                                const float* __restrict__ vals,
                                const int* __restrict__ offs,
                                int2* __restrict__ bkt_buf, int n_edges) {
    __shared__ int lpos[NBUCKETS];
    for (int i = threadIdx.x; i < NBUCKETS; i += blockDim.x)
        lpos[i] = offs[i * NB + blockIdx.x];
    __syncthreads();
    int stride = gridDim.x * blockDim.x;
    for (int e = blockIdx.x * blockDim.x + threadIdx.x; e < n_edges; e += stride) {
        int r = rows[e];
        int b = ((unsigned)r) >> BSHIFT;
        int pos = atomicAdd(&lpos[b], 1);
        int2 p;
        p.x = cols[e] | ((r & (BROWS - 1)) << 19);   // 19+10 bits < 32
        p.y = __float_as_int(vals[e]);
        bkt_buf[pos] = p;
    }
}

__device__ __forceinline__ int pad8(int x) { return (x + 7) & ~7; }

// One 512-thread block per 1024-row bucket: LDS row hist, 512-wide scan of
// PADDED pair-counts, emit row_span = {beg, beg+pad8(cnt)}, place edges at
// bucket_base(b) + padded intra-bucket offsets, zero-fill the pad slots.
__global__ void scatter2_kernel(const int2* __restrict__ bkt_buf,
                                const int* __restrict__ offs,
                                int2* __restrict__ row_span,
                                int2* __restrict__ csr_cv, int n_edges) {
    __shared__ int lcnt[BROWS];
    __shared__ int lptr[BROWS];
    __shared__ int lfill[BROWS];
    __shared__ int s[512];
    int b = blockIdx.x;
    int t = threadIdx.x;
    int e0 = offs[b * NB];
    int e1 = (b == NBUCKETS - 1) ? n_edges : offs[(b + 1) * NB];
    for (int i = t; i < BROWS; i += 512) { lcnt[i] = 0; lfill[i] = 0; }
    __syncthreads();
    for (int e = e0 + t; e < e1; e += blockDim.x)
        atomicAdd(&lcnt[((unsigned)bkt_buf[e].x) >> 19], 1);
    __syncthreads();
    s[t] = pad8(lcnt[2 * t]) + pad8(lcnt[2 * t + 1]);
    __syncthreads();
    for (int off = 1; off < 512; off <<= 1) {
        int v = (t >= off) ? s[t - off] : 0;
        __syncthreads();
        s[t] += v;                       // inclusive over pairs
        __syncthreads();
    }
    {
        int base = b * BUCKET_CAP + (t ? s[t - 1] : 0);
        int rbase = b << BSHIFT;
        int pe = pad8(lcnt[2 * t]);
        int po = pad8(lcnt[2 * t + 1]);
        int p_even = base;
        int p_odd  = base + pe;
        lptr[2 * t]     = p_even;
        lptr[2 * t + 1] = p_odd;
        if (rbase + 2 * t < N_NODES) {
            int2 sp; sp.x = p_even; sp.y = p_even + pe;
            row_span[rbase + 2 * t] = sp;
        }
        if (rbase + 2 * t + 1 < N_NODES) {
            int2 sp; sp.x = p_odd; sp.y = p_odd + po;
            row_span[rbase + 2 * t + 1] = sp;
        }
    }
    __syncthreads();
    for (int e = e0 + t; e < e1; e += blockDim.x) {
        int2 p = bkt_buf[e];
        int delta = ((unsigned)p.x) >> 19;
        int pos = lptr[delta] + atomicAdd(&lfill[delta], 1);
        int2 cv;
        cv.x = p.x & COLMASK;
        cv.y = p.y;
        csr_cv[pos] = cv;
    }
    __syncthreads();
    // zero-fill pad slots (col 0, val 0): two rows per thread, <=7 each
    for (int i = t; i < BROWS; i += 512) {
        int c  = lcnt[i];
        int cp = pad8(c);
        int p  = lptr[i];
        int2 z; z.x = 0; z.y = 0;
        for (int k = c; k < cp; ++k) csr_cv[p + k] = z;
    }
}

// ---------- SpMV helpers ----------
// fmaf(half2float(h), w, acc) lowers to v_fma_mix_f32 (fp16 src, fp32 MAC).
__device__ __forceinline__ float4 fma_mix4(const ushort* __restrict__ h,
                                           int row, int l16, float w,
                                           float4 acc) {
    uint2 r = ((const uint2*)(h + (size_t)row * DIM))[l16];
    __half2 h01 = *(__half2*)&r.x;
    __half2 h23 = *(__half2*)&r.y;
    acc.x = __builtin_fmaf(__half2float(__low2half(h01)),  w, acc.x);
    acc.y = __builtin_fmaf(__half2float(__high2half(h01)), w, acc.y);
    acc.z = __builtin_fmaf(__half2float(__low2half(h23)),  w, acc.z);
    acc.w = __builtin_fmaf(__half2float(__high2half(h23)), w, acc.w);
    return acc;
}

// Process one 8-edge batch: 4 unconditional int4 loads (rows are padded to
// a multiple of 8 with zero-val entries -> no clamps, no ternaries).
__device__ __forceinline__ float4 batch8(const int2* __restrict__ csr_cv,
                                         const ushort* __restrict__ h_src,
                                         int p, int l16, float4 acc) {
    const int4* q = (const int4*)(csr_cv + p);
    int4 a = q[0], b = q[1], c = q[2], d = q[3];
    acc = fma_mix4(h_src, a.x, l16, __int_as_float(a.y), acc);
    acc = fma_mix4(h_src, a.z, l16, __int_as_float(a.w), acc);
    acc = fma_mix4(h_src, b.x, l16, __int_as_float(b.y), acc);
    acc = fma_mix4(h_src, b.z, l16, __int_as_float(b.w), acc);
    acc = fma_mix4(h_src, c.x, l16, __int_as_float(c.y), acc);
    acc = fma_mix4(h_src, c.z, l16, __int_as_float(c.w), acc);
    acc = fma_mix4(h_src, d.x, l16, __int_as_float(d.y), acc);
    acc = fma_mix4(h_src, d.z, l16, __int_as_float(d.w), acc);
    return acc;
}

#define NWAVES ((N_NODES + 3) / 4)    // spmv waves; tail waves do the gather

// Full-table SpMV: 4 rows/wave (1 per 16-lane group), 8 edges in flight.
// (8-unroll is the proven optimum: 16 raised VGPR 32->40, dropped occ
// 75->59% and added padding waste -> +23% time. Do not deepen.)
// Tail waves (wave >= NWAVES) perform the batch-row gather of h_src
// (u_acc/it_acc init or add) that used to be a separate gather_add launch:
// spmv reads h_src anyway, and the gather is latency-slack work.
__global__ void spmv_csr_kernel(const int2* __restrict__ row_span,
                                const int2* __restrict__ csr_cv,
                                const ushort* __restrict__ h_src,
                                ushort* __restrict__ h_dst,
                                const int* __restrict__ users,
                                const int* __restrict__ items,
                                float* __restrict__ u_acc,
                                float* __restrict__ it_acc,
                                int B, int first) {
    int wave = (int)(((long)blockIdx.x * blockDim.x + threadIdx.x) >> 6);
    int lane = threadIdx.x & 63;
    int g    = lane >> 4;
    int l16  = lane & 15;
    if (wave < NWAVES) {
        int r    = wave * 4 + g;
        int rc   = min(r, N_NODES - 1);
        int2 sp  = row_span[rc];
        int p0   = sp.x;
        int len  = (r < N_NODES) ? (sp.y - sp.x) : 0;   // multiple of 8
        int m = max(len, __shfl_xor(len, 16, 64));
        m = max(m, __shfl_xor(m, 32, 64));
        float4 acc = make_float4(0.f, 0.f, 0.f, 0.f);
        for (int off = 0; off < m; off += 8) {
            if (off < len)
                acc = batch8(csr_cv, h_src, p0 + off, l16, acc);
        }
        if (r < N_NODES) {
            __half2 a = __floats2half2_rn(acc.x, acc.y);
            __half2 b = __floats2half2_rn(acc.z, acc.w);
            uint2 o;
            o.x = *(unsigned*)&a;
            o.y = *(unsigned*)&b;
            ((uint2*)(h_dst + (size_t)r * DIM))[l16] = o;
        }
    } else {
        int s = (wave - NWAVES) * 4 + g;
        if (s >= 2 * B) return;
        int node = (s < B) ? users[s] : (N_USERS + items[s - B]);
        uint2 hr = ((const uint2*)(h_src + (size_t)node * DIM))[l16];
        float2 a01 = __half22float2(*(__half2*)&hr.x);
        float2 a23 = __half22float2(*(__half2*)&hr.y);
        float* dst = (s < B) ? (u_acc + (size_t)s * DIM)
                             : (it_acc + (size_t)(s - B) * DIM);
        float4* p = (float4*)dst + l16;
        if (first) {
            *p = make_float4(a01.x, a01.y, a23.x, a23.y);
        } else {
            float4 o = *p;
            o.x += a01.x; o.y += a01.y; o.z += a23.x; o.w += a23.y;
            *p = o;
        }
    }
}

// Layer-3 SpMV over BATCH ROWS ONLY (~11% of the edges): slot s in [0,2B);
// node = users[s] or N_USERS+items[s-B]. Accumulator is INITIALIZED with the
// h2[node] fragment (this fuses the final gather_add), then accumulates
// A·h2[node], and adds once into u_acc/it_acc (slot owned by one group).
__global__ void spmv_batch_kernel(const int2* __restrict__ row_span,
                                  const int2* __restrict__ csr_cv,
                                  const ushort* __restrict__ h_src,
                                  const int* __restrict__ users,
                                  const int* __restrict__ items,
                                  float* __restrict__ u_acc,
                                  float* __restrict__ it_acc, int B) {
    int wave = (int)(((long)blockIdx.x * blockDim.x + threadIdx.x) >> 6);
    int lane = threadIdx.x & 63;
    int g    = lane >> 4;
    int l16  = lane & 15;
    int s    = wave * 4 + g;
    bool ok  = s < 2 * B;
    int node = 0;
    if (ok) node = (s < B) ? users[s] : (N_USERS + items[s - B]);
    float4 acc = make_float4(0.f, 0.f, 0.f, 0.f);
    if (ok) {
        uint2 hr = ((const uint2*)(h_src + (size_t)node * DIM))[l16];
        float2 a01 = __half22float2(*(__half2*)&hr.x);
        float2 a23 = __half22float2(*(__half2*)&hr.y);
        acc = make_float4(a01.x, a01.y, a23.x, a23.y);
    }
    int2 sp  = row_span[node];
    int p0   = sp.x;
    int len  = ok ? (sp.y - sp.x) : 0;
    int m = max(len, __shfl_xor(len, 16, 64));
    m = max(m, __shfl_xor(m, 32, 64));
    for (int off = 0; off < m; off += 8) {
        if (off < len)
            acc = batch8(csr_cv, h_src, p0 + off, l16, acc);
    }
    if (ok) {
        float* dst = (s < B) ? (u_acc + (size_t)s * DIM)
                             : (it_acc + (size_t)(s - B) * DIM);
        float4* p = (float4*)dst + l16;
        float4 old = *p;
        old.x += acc.x; old.y += acc.y; old.z += acc.z; old.w += acc.w;
        *p = old;
    }
}

__global__ void dot_kernel(const float* __restrict__ u_acc,
                           const float* __restrict__ it_acc,
                           float* __restrict__ out, int B) {
    int gid  = blockIdx.x * blockDim.x + threadIdx.x;
    int b    = gid >> 6;
    int lane = gid & 63;
    if (b >= B) return;
    float p = u_acc[(size_t)b * DIM + lane] * it_acc[(size_t)b * DIM + lane];
    #pragma unroll
    for (int off = 32; off > 0; off >>= 1)
        p += __shfl_down(p, off, 64);
    if (lane == 0) out[b] = p * (1.0f / 16.0f);
}

extern "C" void kernel_launch(void* const* d_in, const int* in_sizes, int n_in,
                              void* d_out, int out_size, void* d_ws, size_t ws_size,
                              hipStream_t stream) {
    const int*   users = (const int*)d_in[0];
    const int*   items = (const int*)d_in[1];
    const int*   erows = (const int*)d_in[2];
    const int*   ecols = (const int*)d_in[3];
    const float* evals = (const float*)d_in[4];
    const float* uemb  = (const float*)d_in[5];
    const float* iemb  = (const float*)d_in[6];
    const float* temb  = (const float*)d_in[7];
    float* out = (float*)d_out;

    const int n_edges = in_sizes[2];
    const int B       = in_sizes[0];

    const size_t h2bytes = (((size_t)N_NODES * DIM * 2 + 255) / 256) * 256;  // 38.4 MB
    const size_t abytes  = (size_t)B * DIM * sizeof(float);                  // 4.2 MB
    const size_t spbytes = (((size_t)N_NODES * 8 + 255) / 256) * 256;        // 2.4 MB
    const size_t csrbytes= (size_t)NBUCKETS * BUCKET_CAP * 8;                // 57.8 MB
    const size_t bkbytes = (size_t)n_edges * 8;                              // 40 MB
    const size_t mbytes  = (((size_t)M_TOT * 4 + 255) / 256) * 256;          // 0.6 MB

    char* ws = (char*)d_ws;
    size_t off = 0;
    ushort* hA       = (ushort*)(ws + off); off += h2bytes;
    ushort* hB       = (ushort*)(ws + off); off += h2bytes;
    float*  u_acc    = (float*) (ws + off); off += abytes;
    float*  it_acc   = (float*) (ws + off); off += abytes;
    int2*   row_span = (int2*)  (ws + off); off += spbytes;
    int2*   csr_cv   = (int2*)  (ws + off); off += csrbytes;
    int2*   bkt_buf  = (int2*)  (ws + off); off += bkbytes;
    int*    partial  = (int*)   (ws + off); off += mbytes;
    int*    offs     = (int*)   (ws + off); off += mbytes;
    int*    psum     = (int*)   (ws + off); off += 4096;   // ~186 MB total

    dim3 blk(256);
    dim3 blk512(512);

    // ---- CSR build (zero global atomics) + h0 concat fused into hist ----
    const long n4 = (long)N_NODES * DIM / 4;
    const int  nconcat = (int)((n4 + 511) / 512);
    prep_kernel<<<NB + nconcat, blk512, 0, stream>>>(erows, partial, n_edges,
                                                     uemb, iemb, temb, hA);
    scanB1_kernel<<<SB, blk, 0, stream>>>(partial, psum);
    scanB3_kernel<<<SB, blk, 0, stream>>>(partial, psum, offs);
    scatter1_kernel<<<NB, blk512, 0, stream>>>(erows, ecols, evals, offs, bkt_buf, n_edges);
    scatter2_kernel<<<NBUCKETS, blk512, 0, stream>>>(bkt_buf, offs, row_span, csr_cv, n_edges);

    // ---- layers 1,2: full-table SpMV (+fused batch gather of h_src);
    //      layer 3: batch rows only (+fused h2 gather via acc init) ----
    const int gwaves  = (2 * B + 3) / 4;
    const int fblocks = (int)(((long)(NWAVES + gwaves) * 64 + 255) / 256);
    spmv_csr_kernel<<<fblocks, blk, 0, stream>>>(row_span, csr_cv, hA, hB,
                                                 users, items, u_acc, it_acc, B, 1);
    spmv_csr_kernel<<<fblocks, blk, 0, stream>>>(row_span, csr_cv, hB, hA,
                                                 users, items, u_acc, it_acc, B, 0);
    const int bblocks = (int)(((long)gwaves * 64 + 255) / 256);
    spmv_batch_kernel<<<bblocks, blk, 0, stream>>>(row_span, csr_cv, hA,
                                                   users, items, u_acc, it_acc, B);

    dot_kernel<<<(B * 64 + 255) / 256, blk, 0, stream>>>(u_acc, it_acc, out, B);
}